// Round 1
// baseline (17106.845 us; speedup 1.0000x reference)
//
#include <hip/hip_runtime.h>

#define T_STEPS 32768
#define DIN 256
#define HID 64
#define G3 192
#define JJ 1024
#define PF 4          // gi register-prefetch depth (steps ahead)

typedef float f4 __attribute__((ext_vector_type(4)));

__device__ __forceinline__ float hsum4(f4 v) { return (v.x + v.y) + (v.z + v.w); }

// ---------------- K1: gi = x @ w_ih^T + b_ih  (T x 192) ----------------
__global__ __launch_bounds__(192)
void k_gi(const float* __restrict__ states, const float* __restrict__ w_ih,
          const float* __restrict__ b_ih, float* __restrict__ gi)
{
    __shared__ __align__(16) float xs[32 * DIN];   // 32 KB x-tile
    const int tid  = threadIdx.x;
    const int row0 = blockIdx.x * 32;

    for (int i = tid; i < 32 * DIN; i += 192)
        xs[i] = states[(size_t)(row0 + (i >> 8)) * (DIN + 3) + (i & 255)];
    __syncthreads();

    const int c = tid;                 // one output column per thread
    float acc[32];
#pragma unroll
    for (int r = 0; r < 32; ++r) acc[r] = 0.f;

    for (int k4 = 0; k4 < DIN / 4; ++k4) {
        const float4 wv = *(const float4*)&w_ih[c * DIN + k4 * 4];
#pragma unroll
        for (int r = 0; r < 32; ++r) {
            const float4 xv = *(const float4*)&xs[r * DIN + k4 * 4];  // LDS broadcast
            acc[r] += xv.x * wv.x + xv.y * wv.y + xv.z * wv.z + xv.w * wv.w;
        }
    }
    const float bi = b_ih[c];
#pragma unroll
    for (int r = 0; r < 32; ++r)
        gi[(size_t)(row0 + r) * G3 + c] = acc[r] + bi;
}

// ---------------- K2: sequential GRU scan -----------------------------------
// Single wave, no barriers. Lane t owns w_hh rows t / t+64 / t+128 as 48 NAMED
// float4 SSA values. flat_work_group_size + waves_per_eu(1,1) hands the
// allocator the full 512-VGPR file so they stay register-resident.
// Gate-major schedule: r-matvec -> r-sigmoid issues early and its exp/rcp
// latency hides under the z/n matvec issue; z-sigmoid hides under n-matvec;
// only the final tanh is exposed. All sigmoids/tanh use v_exp_f32 + v_rcp_f32
// (no IEEE div sequences on the serial chain).
#define Q16(M) M(0) M(1) M(2) M(3) M(4) M(5) M(6) M(7) \
               M(8) M(9) M(10) M(11) M(12) M(13) M(14) M(15)
#define QA16(M) M(0,a) M(1,b) M(2,a) M(3,b) M(4,a) M(5,b) M(6,a) M(7,b) \
                M(8,a) M(9,b) M(10,a) M(11,b) M(12,a) M(13,b) M(14,a) M(15,b)

__global__ __attribute__((amdgpu_flat_work_group_size(64, 64), amdgpu_waves_per_eu(1, 1)))
void k_scan(const float* __restrict__ gi, const float* __restrict__ w_hh,
            const float* __restrict__ b_hh, const float* __restrict__ h0,
            float* __restrict__ hs, float* __restrict__ h_final)
{
    __shared__ __align__(64) float h_lds[HID];
    const int t = threadIdx.x;           // 0..63

    // 48 named float4 weight fragments -> 192 VGPRs, SSA
#define DECLW(q) f4 wr##q, wz##q, wn##q;
    Q16(DECLW)
#undef DECLW
    {
        const float* r0 = w_hh + (size_t)t * HID;
        const float* r1 = w_hh + (size_t)(t + 64) * HID;
        const float* r2 = w_hh + (size_t)(t + 128) * HID;
#define LOADW(q) wr##q = *(const f4*)&r0[q * 4]; \
                 wz##q = *(const f4*)&r1[q * 4]; \
                 wn##q = *(const f4*)&r2[q * 4];
        Q16(LOADW)
#undef LOADW
    }
    const float bhr = b_hh[t];
    const float bhz = b_hh[t + 64];
    const float bhn = b_hh[t + 128];

    const float LOG2E  =  1.44269504088896340736f;
    const float NLOG2E = -1.44269504088896340736f;
    const float crb = NLOG2E * bhr;      // bias pre-folded into exp2 argument
    const float czb = NLOG2E * bhz;

    float hv = h0[t];
    h_lds[t] = hv;                       // in-order DS: visible to step-0 reads

    // rotating gi prefetch, PF steps ahead
    const float* gp = gi + t;
    float pr[PF], pz[PF], pn[PF];
#pragma unroll
    for (int j = 0; j < PF; ++j) {
        pr[j] = gp[(size_t)j * G3];
        pz[j] = gp[(size_t)j * G3 + 64];
        pn[j] = gp[(size_t)j * G3 + 128];
    }

    float* hsp = hs + t;

#pragma unroll PF
    for (int s = 0; s < T_STEPS; ++s) {
        const int j = s & (PF - 1);
        const float gir = pr[j], giz = pz[j], gin = pn[j];

        const int sp = (s + PF) & (T_STEPS - 1);   // wraps: address stays valid
        pr[j] = gp[(size_t)sp * G3];
        pz[j] = gp[(size_t)sp * G3 + 64];
        pn[j] = gp[(size_t)sp * G3 + 128];

        // broadcast-read all 16 h quads once (in-order DS behind prev write);
        // kept live across the three gate matvecs (64 VGPRs)
#define RDH(q) const f4 hq##q = *(const f4*)&h_lds[q * 4];
        Q16(RDH)
#undef RDH

        // off-chain sigmoid pre-constants (ready before the sums finish)
        const float cr = __builtin_fmaf(NLOG2E, gir, crb);
        const float cz = __builtin_fmaf(NLOG2E, giz, czb);

        // ---- r-gate matvec: two 8-deep chains ----
        f4 ra = {0.f,0.f,0.f,0.f}, rb = {0.f,0.f,0.f,0.f};
#define MR(q, A) r##A = __builtin_elementwise_fma(wr##q, hq##q, r##A);
        QA16(MR)
#undef MR
        // r-sigmoid issues NOW; its exp/rcp latency hides under z/n matvec issue
        const float sr = hsum4(ra + rb);
        const float er = __builtin_amdgcn_exp2f(__builtin_fmaf(sr, NLOG2E, cr));
        const float r  = __builtin_amdgcn_rcpf(1.f + er);

        // ---- z-gate matvec ----
        f4 za = {0.f,0.f,0.f,0.f}, zb = {0.f,0.f,0.f,0.f};
#define MZ(q, A) z##A = __builtin_elementwise_fma(wz##q, hq##q, z##A);
        QA16(MZ)
#undef MZ

        // ---- n-gate matvec ----
        f4 na = {0.f,0.f,0.f,0.f}, nb = {0.f,0.f,0.f,0.f};
#define MN(q, A) n##A = __builtin_elementwise_fma(wn##q, hq##q, n##A);
        QA16(MN)
#undef MN

        // z-sigmoid (exp hides under n-matvec issue)
        const float sz = hsum4(za + zb);
        const float ez = __builtin_amdgcn_exp2f(__builtin_fmaf(sz, NLOG2E, cz));
        const float z  = __builtin_amdgcn_rcpf(1.f + ez);

        // n-gate tanh: the only exposed transcendental chain
        const float anb  = hsum4(na + nb) + bhn;
        const float npre = __builtin_fmaf(r, anb, gin);
        const float u    = __builtin_amdgcn_exp2f(npre * (2.f * LOG2E));  // e^(2x)
        const float n    = __builtin_fmaf(-2.f, __builtin_amdgcn_rcpf(u + 1.f), 1.f);

        hv = __builtin_fmaf(z, hv - n, n);   // (1-z)*n + z*h

        h_lds[t] = hv;                    // for next step (in-order DS pipe)
        hsp[(size_t)s * HID] = hv;        // fire-and-forget, coalesced 256 B
    }
    h_final[t] = hv;
}

// ---------------- K3: logits = hs @ w_out^T + b_out, masked ----------------
__global__ __launch_bounds__(256)
void k_out(const float* __restrict__ hs, const float* __restrict__ w_out,
           const float* __restrict__ b_out, const int* __restrict__ mask,
           float* __restrict__ out)
{
    __shared__ __align__(16) float hs_s[16 * HID];
    const int tid  = threadIdx.x;
    const int row0 = blockIdx.x * 16;

    {   // stage 16 rows of hs (contiguous 1024 floats)
        const float4 v = *(const float4*)&hs[(size_t)row0 * HID + tid * 4];
        *(float4*)&hs_s[tid * 4] = v;
    }
    __syncthreads();

    float acc[16][4];
#pragma unroll
    for (int r = 0; r < 16; ++r)
#pragma unroll
        for (int cc = 0; cc < 4; ++cc) acc[r][cc] = 0.f;

    for (int k4 = 0; k4 < HID / 4; ++k4) {
        float4 wv[4];
#pragma unroll
        for (int cc = 0; cc < 4; ++cc)
            wv[cc] = *(const float4*)&w_out[(size_t)(cc * 256 + tid) * HID + k4 * 4];
#pragma unroll
        for (int r = 0; r < 16; ++r) {
            const float4 hv = *(const float4*)&hs_s[r * HID + k4 * 4];  // broadcast
#pragma unroll
            for (int cc = 0; cc < 4; ++cc)
                acc[r][cc] += hv.x * wv[cc].x + hv.y * wv[cc].y +
                              hv.z * wv[cc].z + hv.w * wv[cc].w;
        }
    }

#pragma unroll
    for (int cc = 0; cc < 4; ++cc) {
        const int c = cc * 256 + tid;
        const float bo = b_out[c];
        const int m = mask[c];
#pragma unroll
        for (int r = 0; r < 16; ++r) {
            const float v = (m == 0) ? -1e9f : (acc[r][cc] + bo);
            out[(size_t)(row0 + r) * JJ + c] = v;
        }
    }
}

// ---------------- launch ----------------
extern "C" void kernel_launch(void* const* d_in, const int* in_sizes, int n_in,
                              void* d_out, int out_size, void* d_ws, size_t ws_size,
                              hipStream_t stream)
{
    const float* states = (const float*)d_in[0];
    const float* h0     = (const float*)d_in[1];
    const float* w_ih   = (const float*)d_in[2];
    const float* w_hh   = (const float*)d_in[3];
    const float* b_ih   = (const float*)d_in[4];
    const float* b_hh   = (const float*)d_in[5];
    const float* w_out  = (const float*)d_in[6];
    const float* b_out  = (const float*)d_in[7];
    const int*   mask   = (const int*)d_in[8];

    float* out = (float*)d_out;
    float* gi  = (float*)d_ws;                         // T*192 fp32 = 25.2 MB
    float* hs  = gi + (size_t)T_STEPS * G3;            // T*64  fp32 =  8.4 MB
    float* h_final = out + (size_t)T_STEPS * JJ;       // after logits

    k_gi  <<<dim3(T_STEPS / 32), dim3(192), 0, stream>>>(states, w_ih, b_ih, gi);
    k_scan<<<dim3(1),            dim3(64),  0, stream>>>(gi, w_hh, b_hh, h0, hs, h_final);
    k_out <<<dim3(T_STEPS / 16), dim3(256), 0, stream>>>(hs, w_out, b_out, mask, out);
}

// Round 2
// 11986.546 us; speedup vs baseline: 1.4272x; 1.4272x over previous
//
#include <hip/hip_runtime.h>

#define T_STEPS 32768
#define DIN 256
#define HID 64
#define G3 192
#define JJ 1024
#define PF 4          // gi register-prefetch depth (steps ahead)

typedef float f4 __attribute__((ext_vector_type(4)));

__device__ __forceinline__ float hsum4(f4 v) { return (v.x + v.y) + (v.z + v.w); }

// ---------------- K1: gi = x @ w_ih^T + b_ih  (T x 192) ----------------
__global__ __launch_bounds__(192)
void k_gi(const float* __restrict__ states, const float* __restrict__ w_ih,
          const float* __restrict__ b_ih, float* __restrict__ gi)
{
    __shared__ __align__(16) float xs[32 * DIN];   // 32 KB x-tile
    const int tid  = threadIdx.x;
    const int row0 = blockIdx.x * 32;

    for (int i = tid; i < 32 * DIN; i += 192)
        xs[i] = states[(size_t)(row0 + (i >> 8)) * (DIN + 3) + (i & 255)];
    __syncthreads();

    const int c = tid;                 // one output column per thread
    float acc[32];
#pragma unroll
    for (int r = 0; r < 32; ++r) acc[r] = 0.f;

    for (int k4 = 0; k4 < DIN / 4; ++k4) {
        const float4 wv = *(const float4*)&w_ih[c * DIN + k4 * 4];
#pragma unroll
        for (int r = 0; r < 32; ++r) {
            const float4 xv = *(const float4*)&xs[r * DIN + k4 * 4];  // LDS broadcast
            acc[r] += xv.x * wv.x + xv.y * wv.y + xv.z * wv.z + xv.w * wv.w;
        }
    }
    const float bi = b_ih[c];
#pragma unroll
    for (int r = 0; r < 32; ++r)
        gi[(size_t)(row0 + r) * G3 + c] = acc[r] + bi;
}

// ---------------- K2: sequential GRU scan, 4-wave K-split -------------------
// 256 threads = 4 waves, one per SIMD of the CU. Wave w owns K-chunk
// h[16w..16w+15]: lane t holds W[t,kc], W[t+64,kc], W[t+128,kc] as 12 f4
// (48 VGPRs, quad-major interleave = low register pressure, proven schedule).
// Per step:
//   - each wave reads its 4 h-quads from ITS OWN LDS h copy (same-wave
//     in-order DS pipe -> no barrier on the h path),
//   - 12 f4-FMAs -> 3 partial sums/lane -> published to a double-buffered
//     partial array,
//   - ONE raw s_barrier (s_waitcnt lgkmcnt(0) only -- NOT __syncthreads(),
//     which drains vmcnt(0) and would stall the gi prefetch every step),
//   - every wave reads all 4 partials/gate (ds_read_b128), computes the
//     gates redundantly (identical hv in all waves), writes its own h copy.
// Double-buffered partials make a one-step wave lead safe; a two-step lead
// is impossible through the barrier.
__global__ __launch_bounds__(256)
void k_scan(const float* __restrict__ gi, const float* __restrict__ w_hh,
            const float* __restrict__ b_hh, const float* __restrict__ h0,
            float* __restrict__ hs, float* __restrict__ h_final)
{
    __shared__ __align__(16) float hsh[4][HID];          // per-wave h copy (1 KB)
    __shared__ __align__(16) float pbuf[2][3][HID][4];   // [parity][gate][t][w] (6 KB)

    const int tid = threadIdx.x;
    const int w   = tid >> 6;            // wave id 0..3
    const int t   = tid & 63;            // lane id = output element

    // weights: rows t / t+64 / t+128, cols 16w..16w+15  -> 12 named f4
    f4 wr0, wr1, wr2, wr3, wz0, wz1, wz2, wz3, wn0, wn1, wn2, wn3;
    {
        const float* r0 = w_hh + (size_t)t         * HID + w * 16;
        const float* r1 = w_hh + (size_t)(t + 64)  * HID + w * 16;
        const float* r2 = w_hh + (size_t)(t + 128) * HID + w * 16;
        wr0 = *(const f4*)&r0[0];  wr1 = *(const f4*)&r0[4];
        wr2 = *(const f4*)&r0[8];  wr3 = *(const f4*)&r0[12];
        wz0 = *(const f4*)&r1[0];  wz1 = *(const f4*)&r1[4];
        wz2 = *(const f4*)&r1[8];  wz3 = *(const f4*)&r1[12];
        wn0 = *(const f4*)&r2[0];  wn1 = *(const f4*)&r2[4];
        wn2 = *(const f4*)&r2[8];  wn3 = *(const f4*)&r2[12];
    }
    const float bhr = b_hh[t];
    const float bhz = b_hh[t + 64];
    const float bhn = b_hh[t + 128];

    const float LOG2E  =  1.44269504088896340736f;
    const float NLOG2E = -1.44269504088896340736f;
    const float crb = NLOG2E * bhr;      // sigmoid bias pre-folded into exp2 arg
    const float czb = NLOG2E * bhz;

    float hv = h0[t];
    hsh[w][t] = hv;                      // own copy; same-wave in-order DS

    // rotating gi prefetch, PF steps ahead (each wave redundantly; L3 hits)
    const float* gp = gi + t;
    float pr[PF], pz[PF], pn[PF];
#pragma unroll
    for (int j = 0; j < PF; ++j) {
        pr[j] = gp[(size_t)j * G3];
        pz[j] = gp[(size_t)j * G3 + 64];
        pn[j] = gp[(size_t)j * G3 + 128];
    }

    float* hsp = hs + t;
    const float* hloc = &hsh[w][w * 16];         // this wave's K-chunk (uniform addr)
    const bool do_st = ((t >> 4) == w);          // lane-predicated hs store:
                                                 // static instruction flow, static vmcnt

#pragma unroll PF
    for (int s = 0; s < T_STEPS; ++s) {
        const int j = s & (PF - 1);
        const float gir = pr[j], giz = pz[j], gin = pn[j];

        const int sp = (s + PF) & (T_STEPS - 1);   // wraps: address stays valid
        pr[j] = gp[(size_t)sp * G3];
        pz[j] = gp[(size_t)sp * G3 + 64];
        pn[j] = gp[(size_t)sp * G3 + 128];

        // ---- local matvec on own 16-wide K-chunk (quad-major interleave) ----
        const f4 hq0 = *(const f4*)&hloc[0];
        const f4 hq1 = *(const f4*)&hloc[4];
        const f4 hq2 = *(const f4*)&hloc[8];
        const f4 hq3 = *(const f4*)&hloc[12];

        f4 ar4 = {0.f,0.f,0.f,0.f};
        f4 az4 = {0.f,0.f,0.f,0.f};
        f4 an4 = {0.f,0.f,0.f,0.f};
        ar4 = __builtin_elementwise_fma(wr0, hq0, ar4);
        az4 = __builtin_elementwise_fma(wz0, hq0, az4);
        an4 = __builtin_elementwise_fma(wn0, hq0, an4);
        ar4 = __builtin_elementwise_fma(wr1, hq1, ar4);
        az4 = __builtin_elementwise_fma(wz1, hq1, az4);
        an4 = __builtin_elementwise_fma(wn1, hq1, an4);
        ar4 = __builtin_elementwise_fma(wr2, hq2, ar4);
        az4 = __builtin_elementwise_fma(wz2, hq2, az4);
        an4 = __builtin_elementwise_fma(wn2, hq2, an4);
        ar4 = __builtin_elementwise_fma(wr3, hq3, ar4);
        az4 = __builtin_elementwise_fma(wz3, hq3, az4);
        an4 = __builtin_elementwise_fma(wn3, hq3, an4);

        // ---- publish partials (double-buffered) ----
        float* pb = &pbuf[s & 1][0][0][0];
        pb[(0 * HID + t) * 4 + w] = hsum4(ar4);
        pb[(1 * HID + t) * 4 + w] = hsum4(az4);
        pb[(2 * HID + t) * 4 + w] = hsum4(an4);

        // raw barrier: wait LDS writes only; vmcnt (gi prefetch) stays in flight
        asm volatile("s_waitcnt lgkmcnt(0)\n\ts_barrier" ::: "memory");

        // ---- reduce partials + gates (redundant in all waves) ----
        const f4 pr4 = *(const f4*)&pb[(0 * HID + t) * 4];
        const f4 pz4 = *(const f4*)&pb[(1 * HID + t) * 4];
        const f4 pn4 = *(const f4*)&pb[(2 * HID + t) * 4];

        const float cr = __builtin_fmaf(NLOG2E, gir, crb);
        const float cz = __builtin_fmaf(NLOG2E, giz, czb);

        const float ar = hsum4(pr4);
        const float er = __builtin_amdgcn_exp2f(__builtin_fmaf(ar, NLOG2E, cr));
        const float r  = __builtin_amdgcn_rcpf(1.f + er);

        const float az = hsum4(pz4);
        const float ez = __builtin_amdgcn_exp2f(__builtin_fmaf(az, NLOG2E, cz));
        const float z  = __builtin_amdgcn_rcpf(1.f + ez);

        const float an   = hsum4(pn4) + bhn;
        const float npre = __builtin_fmaf(r, an, gin);
        const float u    = __builtin_amdgcn_exp2f(npre * (2.f * LOG2E)); // e^(2x)
        const float n    = __builtin_fmaf(-2.f, __builtin_amdgcn_rcpf(u + 1.f), 1.f);

        hv = __builtin_fmaf(z, hv - n, n);   // (1-z)*n + z*h

        hsh[w][t] = hv;                   // own copy for next step (in-order DS)
        if (do_st) hsp[(size_t)s * HID] = hv;   // 16 lanes/wave -> full 256 B row
    }
    if (w == 0) h_final[t] = hv;
}

// ---------------- K3: logits = hs @ w_out^T + b_out, masked ----------------
__global__ __launch_bounds__(256)
void k_out(const float* __restrict__ hs, const float* __restrict__ w_out,
           const float* __restrict__ b_out, const int* __restrict__ mask,
           float* __restrict__ out)
{
    __shared__ __align__(16) float hs_s[16 * HID];
    const int tid  = threadIdx.x;
    const int row0 = blockIdx.x * 16;

    {   // stage 16 rows of hs (contiguous 1024 floats)
        const float4 v = *(const float4*)&hs[(size_t)row0 * HID + tid * 4];
        *(float4*)&hs_s[tid * 4] = v;
    }
    __syncthreads();

    float acc[16][4];
#pragma unroll
    for (int r = 0; r < 16; ++r)
#pragma unroll
        for (int cc = 0; cc < 4; ++cc) acc[r][cc] = 0.f;

    for (int k4 = 0; k4 < HID / 4; ++k4) {
        float4 wv[4];
#pragma unroll
        for (int cc = 0; cc < 4; ++cc)
            wv[cc] = *(const float4*)&w_out[(size_t)(cc * 256 + tid) * HID + k4 * 4];
#pragma unroll
        for (int r = 0; r < 16; ++r) {
            const float4 hv = *(const float4*)&hs_s[r * HID + k4 * 4];  // broadcast
#pragma unroll
            for (int cc = 0; cc < 4; ++cc)
                acc[r][cc] += hv.x * wv[cc].x + hv.y * wv[cc].y +
                              hv.z * wv[cc].z + hv.w * wv[cc].w;
        }
    }

#pragma unroll
    for (int cc = 0; cc < 4; ++cc) {
        const int c = cc * 256 + tid;
        const float bo = b_out[c];
        const int m = mask[c];
#pragma unroll
        for (int r = 0; r < 16; ++r) {
            const float v = (m == 0) ? -1e9f : (acc[r][cc] + bo);
            out[(size_t)(row0 + r) * JJ + c] = v;
        }
    }
}

// ---------------- launch ----------------
extern "C" void kernel_launch(void* const* d_in, const int* in_sizes, int n_in,
                              void* d_out, int out_size, void* d_ws, size_t ws_size,
                              hipStream_t stream)
{
    const float* states = (const float*)d_in[0];
    const float* h0     = (const float*)d_in[1];
    const float* w_ih   = (const float*)d_in[2];
    const float* w_hh   = (const float*)d_in[3];
    const float* b_ih   = (const float*)d_in[4];
    const float* b_hh   = (const float*)d_in[5];
    const float* w_out  = (const float*)d_in[6];
    const float* b_out  = (const float*)d_in[7];
    const int*   mask   = (const int*)d_in[8];

    float* out = (float*)d_out;
    float* gi  = (float*)d_ws;                         // T*192 fp32 = 25.2 MB
    float* hs  = gi + (size_t)T_STEPS * G3;            // T*64  fp32 =  8.4 MB
    float* h_final = out + (size_t)T_STEPS * JJ;       // after logits

    k_gi  <<<dim3(T_STEPS / 32), dim3(192), 0, stream>>>(states, w_ih, b_ih, gi);
    k_scan<<<dim3(1),            dim3(256), 0, stream>>>(gi, w_hh, b_hh, h0, hs, h_final);
    k_out <<<dim3(T_STEPS / 16), dim3(256), 0, stream>>>(hs, w_out, b_out, mask, out);
}